// Round 6
// baseline (1422.317 us; speedup 1.0000x reference)
//
#include <hip/hip_runtime.h>
#include <hip/hip_bf16.h>

#define HD 128

typedef __bf16 bf16x8 __attribute__((ext_vector_type(8)));
typedef float f32x4 __attribute__((ext_vector_type(4)));
typedef unsigned uintx4 __attribute__((ext_vector_type(4)));

union Frag { bf16x8 b; uintx4 u4; };

__device__ inline unsigned short f2bf(float f) {
  return __builtin_bit_cast(unsigned short, (__bf16)f);  // RNE, v_cvt path
}
__device__ inline float bf2f(unsigned short h) {
  return __builtin_bit_cast(float, (unsigned)h << 16);
}
__device__ inline unsigned pkbf(float lo, float hi) {  // -> v_cvt_pk_bf16_f32
  return (unsigned)f2bf(lo) | ((unsigned)f2bf(hi) << 16);
}

// ---------------- weight prep: fp32 [K][N] -> bf16 hi/lo transposed [N][K] ----------------
__global__ void k_prep(const float* __restrict__ w, unsigned short* __restrict__ hi,
                       unsigned short* __restrict__ lo, int K, int N) {
  int idx = blockIdx.x * 256 + threadIdx.x;
  if (idx >= K * N) return;
  int nn = idx / K, k = idx - nn * K;
  float v = w[k * N + nn];
  unsigned short h = f2bf(v);
  hi[idx] = h;
  lo[idx] = f2bf(v - bf2f(h));
}

// ---------------- CSR build ----------------
__global__ void k_count(const int* __restrict__ tgt, int* __restrict__ cnt, int E) {
  int e = blockIdx.x * 256 + threadIdx.x;
  if (e < E) atomicAdd(&cnt[tgt[e]], 1);
}

__global__ void k_scan1(const int* __restrict__ cnt, int* __restrict__ rowptr,
                        int* __restrict__ partial, int n) {
  __shared__ int lds[1024];
  int i = blockIdx.x * 1024 + threadIdx.x;
  int v = (i < n) ? cnt[i] : 0;
  lds[threadIdx.x] = v;
  __syncthreads();
  for (int off = 1; off < 1024; off <<= 1) {
    int t = (threadIdx.x >= (unsigned)off) ? lds[threadIdx.x - off] : 0;
    __syncthreads();
    lds[threadIdx.x] += t;
    __syncthreads();
  }
  if (i < n) rowptr[i] = lds[threadIdx.x] - v;  // exclusive
  if (threadIdx.x == 1023) partial[blockIdx.x] = lds[1023];
}

__global__ void k_scan2(int* __restrict__ partial, int nb) {
  __shared__ int lds[1024];
  int v = (threadIdx.x < (unsigned)nb) ? partial[threadIdx.x] : 0;
  lds[threadIdx.x] = v;
  __syncthreads();
  for (int off = 1; off < 1024; off <<= 1) {
    int t = (threadIdx.x >= (unsigned)off) ? lds[threadIdx.x - off] : 0;
    __syncthreads();
    lds[threadIdx.x] += t;
    __syncthreads();
  }
  if (threadIdx.x < (unsigned)nb) partial[threadIdx.x] = lds[threadIdx.x] - v;
}

__global__ void k_scan3(int* __restrict__ rowptr, const int* __restrict__ partial, int n, int E) {
  int i = blockIdx.x * 1024 + threadIdx.x;
  if (i < n) rowptr[i] += partial[blockIdx.x];
  if (blockIdx.x == 0 && threadIdx.x == 0) rowptr[n] = E;
}

__global__ void k_deg(const int* __restrict__ cnt, float* __restrict__ dinv,
                      float* __restrict__ invdeg, int n) {
  int i = blockIdx.x * 256 + threadIdx.x;
  if (i < n) {
    float d = (float)(cnt[i] + 1);  // +1 self loop
    dinv[i] = rsqrtf(d);
    invdeg[i] = 1.0f / d;
  }
}

// fill CSR (sorted by tgt): src, tgt, orig edge id, permuted ea, per-edge norm
__global__ void k_fill3(const int* __restrict__ src, const int* __restrict__ tgt,
                        const int* __restrict__ rowptr, int* __restrict__ cursor,
                        const float* __restrict__ dinv, const float* __restrict__ ea,
                        int* __restrict__ csrc, int* __restrict__ ctgt, int* __restrict__ ceid,
                        float* __restrict__ cea, float* __restrict__ csrnorm, int E) {
  int e = blockIdx.x * 256 + threadIdx.x;
  if (e < E) {
    int t = tgt[e], s = src[e];
    int pos = atomicAdd(&cursor[t], 1);
    int idx = rowptr[t] + pos;
    csrc[idx] = s;
    ctgt[idx] = t;
    ceid[idx] = e;
    csrnorm[idx] = dinv[s] * dinv[t];
    const float* pe = ea + (size_t)e * 5;
    float* po = cea + (size_t)idx * 5;
    po[0] = pe[0]; po[1] = pe[1]; po[2] = pe[2]; po[3] = pe[3]; po[4] = pe[4];
  }
}

// ---------------- node encoder: h = relu(LN(x@W + b)) -> bf16 hi/lo ----------------
__global__ void k_encoder(const float* __restrict__ x, const float* __restrict__ w,
                          const float* __restrict__ b, const float* __restrict__ lng,
                          const float* __restrict__ lnb, unsigned short* __restrict__ hhi,
                          unsigned short* __restrict__ hlo, int n) {
  __shared__ float xs[4 * 34];
  __shared__ float red[4][2][2];
  int g = threadIdx.x >> 7, j = threadIdx.x & 127;
  int node = blockIdx.x * 4 + g;
  int base = blockIdx.x * 4 * 34;
  if (threadIdx.x < 4 * 34) {
    int idx = base + threadIdx.x;
    xs[threadIdx.x] = (idx < n * 34) ? x[idx] : 0.f;
  }
  __syncthreads();
  float acc = b[j];
#pragma unroll
  for (int k = 0; k < 34; k++) acc = fmaf(xs[g * 34 + k], w[k * HD + j], acc);
  int lane = threadIdx.x & 63;
  int wg = (threadIdx.x >> 6) & 1;
  float s = acc, q = acc * acc;
#pragma unroll
  for (int off = 32; off; off >>= 1) { s += __shfl_xor(s, off); q += __shfl_xor(q, off); }
  if (lane == 0) { red[g][wg][0] = s; red[g][wg][1] = q; }
  __syncthreads();
  float st = red[g][0][0] + red[g][1][0], qt = red[g][0][1] + red[g][1][1];
  float mu = st * (1.f / HD);
  float var = qt * (1.f / HD) - mu * mu;
  float y = (acc - mu) * rsqrtf(var + 1e-5f) * lng[j] + lnb[j];
  if (node < n) {
    size_t idx = (size_t)node * HD + j;
    float r = fmaxf(y, 0.f);
    unsigned short hh = f2bf(r);
    hhi[idx] = hh;
    hlo[idx] = f2bf(r - bf2f(hh));
  }
}

// ---------------- GCN neighbor aggregation (wave-per-node, 8-row unroll) ----------
// agg[t] = invdeg[t]*(hhi+hlo)[t] + sum_{s in N(t)} norm * hhi[s]   -> bf16 hi/lo
__global__ __launch_bounds__(256) void k_agg4(
    const unsigned short* __restrict__ hhi, const unsigned short* __restrict__ hlo,
    const int* __restrict__ rowptr, const int* __restrict__ csr,
    const float* __restrict__ csrnorm, const float* __restrict__ invdeg,
    unsigned short* __restrict__ agghi, unsigned short* __restrict__ agglo, int n) {
  int lane = threadIdx.x & 63, wv = threadIdx.x >> 6;
  int q = lane >> 4, c = lane & 15;
  int node = blockIdx.x * 4 + wv;
  if (node >= n) return;
  int e0 = rowptr[node], e1 = rowptr[node + 1];
  // hoist self-row + invdeg loads: latency overlaps the neighbor loop
  size_t base = (size_t)node * 128 + c * 8;
  uintx4 shv = *(const uintx4*)(hhi + base);
  uintx4 slv = *(const uintx4*)(hlo + base);
  float iv = invdeg[node];
  float acc[8] = {0, 0, 0, 0, 0, 0, 0, 0};
  int e = e0 + q;
  for (; e + 28 < e1; e += 32) {
    int s1 = csr[e], s2 = csr[e + 4], s3 = csr[e + 8], s4 = csr[e + 12];
    int s5 = csr[e + 16], s6 = csr[e + 20], s7 = csr[e + 24], s8 = csr[e + 28];
    float n1 = csrnorm[e], n2 = csrnorm[e + 4], n3 = csrnorm[e + 8], n4 = csrnorm[e + 12];
    float n5 = csrnorm[e + 16], n6 = csrnorm[e + 20], n7 = csrnorm[e + 24], n8 = csrnorm[e + 28];
    uintx4 h1 = *(const uintx4*)(hhi + (size_t)s1 * 128 + c * 8);
    uintx4 h2 = *(const uintx4*)(hhi + (size_t)s2 * 128 + c * 8);
    uintx4 h3 = *(const uintx4*)(hhi + (size_t)s3 * 128 + c * 8);
    uintx4 h4 = *(const uintx4*)(hhi + (size_t)s4 * 128 + c * 8);
    uintx4 h5 = *(const uintx4*)(hhi + (size_t)s5 * 128 + c * 8);
    uintx4 h6 = *(const uintx4*)(hhi + (size_t)s6 * 128 + c * 8);
    uintx4 h7 = *(const uintx4*)(hhi + (size_t)s7 * 128 + c * 8);
    uintx4 h8 = *(const uintx4*)(hhi + (size_t)s8 * 128 + c * 8);
#pragma unroll
    for (int d = 0; d < 4; d++) {
      acc[2 * d]     = fmaf(n1, __builtin_bit_cast(float, h1[d] << 16), acc[2 * d]);
      acc[2 * d + 1] = fmaf(n1, __builtin_bit_cast(float, h1[d] & 0xffff0000u), acc[2 * d + 1]);
      acc[2 * d]     = fmaf(n2, __builtin_bit_cast(float, h2[d] << 16), acc[2 * d]);
      acc[2 * d + 1] = fmaf(n2, __builtin_bit_cast(float, h2[d] & 0xffff0000u), acc[2 * d + 1]);
      acc[2 * d]     = fmaf(n3, __builtin_bit_cast(float, h3[d] << 16), acc[2 * d]);
      acc[2 * d + 1] = fmaf(n3, __builtin_bit_cast(float, h3[d] & 0xffff0000u), acc[2 * d + 1]);
      acc[2 * d]     = fmaf(n4, __builtin_bit_cast(float, h4[d] << 16), acc[2 * d]);
      acc[2 * d + 1] = fmaf(n4, __builtin_bit_cast(float, h4[d] & 0xffff0000u), acc[2 * d + 1]);
      acc[2 * d]     = fmaf(n5, __builtin_bit_cast(float, h5[d] << 16), acc[2 * d]);
      acc[2 * d + 1] = fmaf(n5, __builtin_bit_cast(float, h5[d] & 0xffff0000u), acc[2 * d + 1]);
      acc[2 * d]     = fmaf(n6, __builtin_bit_cast(float, h6[d] << 16), acc[2 * d]);
      acc[2 * d + 1] = fmaf(n6, __builtin_bit_cast(float, h6[d] & 0xffff0000u), acc[2 * d + 1]);
      acc[2 * d]     = fmaf(n7, __builtin_bit_cast(float, h7[d] << 16), acc[2 * d]);
      acc[2 * d + 1] = fmaf(n7, __builtin_bit_cast(float, h7[d] & 0xffff0000u), acc[2 * d + 1]);
      acc[2 * d]     = fmaf(n8, __builtin_bit_cast(float, h8[d] << 16), acc[2 * d]);
      acc[2 * d + 1] = fmaf(n8, __builtin_bit_cast(float, h8[d] & 0xffff0000u), acc[2 * d + 1]);
    }
  }
  for (; e < e1; e += 4) {
    int s1 = csr[e];
    float n1 = csrnorm[e];
    uintx4 h1 = *(const uintx4*)(hhi + (size_t)s1 * 128 + c * 8);
#pragma unroll
    for (int d = 0; d < 4; d++) {
      acc[2 * d]     = fmaf(n1, __builtin_bit_cast(float, h1[d] << 16), acc[2 * d]);
      acc[2 * d + 1] = fmaf(n1, __builtin_bit_cast(float, h1[d] & 0xffff0000u), acc[2 * d + 1]);
    }
  }
#pragma unroll
  for (int d = 0; d < 8; d++) {
    acc[d] += __shfl_xor(acc[d], 16);
    acc[d] += __shfl_xor(acc[d], 32);
  }
  uintx4 oh, ol;
#pragma unroll
  for (int d = 0; d < 4; d++) {
    float s0 = __builtin_bit_cast(float, shv[d] << 16) + __builtin_bit_cast(float, slv[d] << 16);
    float s1 = __builtin_bit_cast(float, shv[d] & 0xffff0000u) +
               __builtin_bit_cast(float, slv[d] & 0xffff0000u);
    float v0 = fmaf(iv, s0, acc[2 * d]);
    float v1 = fmaf(iv, s1, acc[2 * d + 1]);
    unsigned short h0 = f2bf(v0), h1 = f2bf(v1);
    oh[d] = (unsigned)h0 | ((unsigned)h1 << 16);
    ol[d] = pkbf(v0 - bf2f(h0), v1 - bf2f(h1));
  }
  if (q == 0) {
    *(uintx4*)(agghi + base) = oh;
    *(uintx4*)(agglo + base) = ol;
  }
}

// ---------------- MFMA GEMM [n,128]@Wt + bias + LN + ReLU + residual -> bf16 hi/lo ------
__global__ __launch_bounds__(256) void k_gemm_ln(
    const unsigned short* __restrict__ Xhi, const unsigned short* __restrict__ Xlo,
    const unsigned short* __restrict__ Whi, const unsigned short* __restrict__ Wlo,
    const float* __restrict__ bias, const float* __restrict__ lng, const float* __restrict__ lnb,
    const unsigned short* __restrict__ hinhi, const unsigned short* __restrict__ hinlo,
    unsigned short* __restrict__ houthi, unsigned short* __restrict__ houtlo, int nrows) {
  int lane = threadIdx.x & 63, wv = threadIdx.x >> 6;
  int q = lane >> 4, c = lane & 15;
  int rowbase = blockIdx.x * 64 + wv * 16;
  Frag ahi[4], alo[4];
  {
    int r = rowbase + c;
    if (r >= nrows) r = nrows - 1;
    const uintx4* ph = (const uintx4*)(Xhi + (size_t)r * 128);
    const uintx4* pl = (const uintx4*)(Xlo + (size_t)r * 128);
#pragma unroll
    for (int ks = 0; ks < 4; ks++) { ahi[ks].u4 = ph[ks * 4 + q]; alo[ks].u4 = pl[ks * 4 + q]; }
  }
  f32x4 acc[8];
#pragma unroll
  for (int nt = 0; nt < 8; nt++) {
    f32x4 a = {0.f, 0.f, 0.f, 0.f};
    int nn = nt * 16 + c;
    const uintx4* pbh = (const uintx4*)(Whi + (size_t)nn * 128);
    const uintx4* pbl = (const uintx4*)(Wlo + (size_t)nn * 128);
#pragma unroll
    for (int ks = 0; ks < 4; ks++) {
      Frag bh, bl;
      bh.u4 = pbh[ks * 4 + q];
      bl.u4 = pbl[ks * 4 + q];
      a = __builtin_amdgcn_mfma_f32_16x16x32_bf16(ahi[ks].b, bh.b, a, 0, 0, 0);
      a = __builtin_amdgcn_mfma_f32_16x16x32_bf16(alo[ks].b, bh.b, a, 0, 0, 0);
      a = __builtin_amdgcn_mfma_f32_16x16x32_bf16(ahi[ks].b, bl.b, a, 0, 0, 0);
    }
    float bv = bias[nn];
#pragma unroll
    for (int r4 = 0; r4 < 4; r4++) acc[nt][r4] = a[r4] + bv;
  }
  float s[4] = {0, 0, 0, 0}, sq[4] = {0, 0, 0, 0};
#pragma unroll
  for (int nt = 0; nt < 8; nt++)
#pragma unroll
    for (int r4 = 0; r4 < 4; r4++) { float v = acc[nt][r4]; s[r4] += v; sq[r4] += v * v; }
#pragma unroll
  for (int off = 1; off <= 8; off <<= 1)
#pragma unroll
    for (int r4 = 0; r4 < 4; r4++) {
      s[r4] += __shfl_xor(s[r4], off);
      sq[r4] += __shfl_xor(sq[r4], off);
    }
  float mu[4], rs[4];
#pragma unroll
  for (int r4 = 0; r4 < 4; r4++) {
    mu[r4] = s[r4] * (1.f / 128.f);
    float var = sq[r4] * (1.f / 128.f) - mu[r4] * mu[r4];
    rs[r4] = rsqrtf(var + 1e-5f);
  }
#pragma unroll
  for (int nt = 0; nt < 8; nt++) {
    int col = nt * 16 + c;
    float gv = lng[col], bb = lnb[col];
#pragma unroll
    for (int r4 = 0; r4 < 4; r4++) {
      int row = rowbase + q * 4 + r4;
      if (row < nrows) {
        size_t idx = (size_t)row * 128 + col;
        float y = (acc[nt][r4] - mu[r4]) * rs[r4] * gv + bb;
        float rr = fmaxf(y, 0.f) + bf2f(hinhi[idx]) + bf2f(hinlo[idx]);
        unsigned short hh = f2bf(rr);
        houthi[idx] = hh;
        houtlo[idx] = f2bf(rr - bf2f(hh));
      }
    }
  }
}

// ---------------- fused A+B projection GEMM (bf16x3 split) -> bf16 out ----------
__global__ __launch_bounds__(256) void k_gemm_mf2(
    const unsigned short* __restrict__ Xhi, const unsigned short* __restrict__ Xlo,
    const unsigned short* __restrict__ Wahi, const unsigned short* __restrict__ Walo,
    const unsigned short* __restrict__ Wbhi, const unsigned short* __restrict__ Wblo,
    const float* __restrict__ biasA, unsigned short* __restrict__ Aout,
    unsigned short* __restrict__ Bout, int nrows) {
  int lane = threadIdx.x & 63, wv = threadIdx.x >> 6;
  int q = lane >> 4, c = lane & 15;
  int rowbase = blockIdx.x * 128 + wv * 32;
  Frag ahi[2][4], alo[2][4];
#pragma unroll
  for (int mt = 0; mt < 2; mt++) {
    int r = rowbase + 16 * mt + c;
    if (r >= nrows) r = nrows - 1;
    const uintx4* ph = (const uintx4*)(Xhi + (size_t)r * 128);
    const uintx4* pl = (const uintx4*)(Xlo + (size_t)r * 128);
#pragma unroll
    for (int ks = 0; ks < 4; ks++) {
      ahi[mt][ks].u4 = ph[ks * 4 + q];
      alo[mt][ks].u4 = pl[ks * 4 + q];
    }
  }
#pragma unroll
  for (int nt = 0; nt < 8; nt++) {
    f32x4 accA0 = {0.f, 0.f, 0.f, 0.f}, accA1 = {0.f, 0.f, 0.f, 0.f};
    f32x4 accB0 = {0.f, 0.f, 0.f, 0.f}, accB1 = {0.f, 0.f, 0.f, 0.f};
    int nn = nt * 16 + c;
    const uintx4* pah = (const uintx4*)(Wahi + (size_t)nn * 128);
    const uintx4* pal = (const uintx4*)(Walo + (size_t)nn * 128);
    const uintx4* pbh = (const uintx4*)(Wbhi + (size_t)nn * 128);
    const uintx4* pbl = (const uintx4*)(Wblo + (size_t)nn * 128);
#pragma unroll
    for (int ks = 0; ks < 4; ks++) {
      Frag ah, al, bh, bl;
      ah.u4 = pah[ks * 4 + q]; al.u4 = pal[ks * 4 + q];
      bh.u4 = pbh[ks * 4 + q]; bl.u4 = pbl[ks * 4 + q];
      accA0 = __builtin_amdgcn_mfma_f32_16x16x32_bf16(ahi[0][ks].b, ah.b, accA0, 0, 0, 0);
      accA0 = __builtin_amdgcn_mfma_f32_16x16x32_bf16(alo[0][ks].b, ah.b, accA0, 0, 0, 0);
      accA0 = __builtin_amdgcn_mfma_f32_16x16x32_bf16(ahi[0][ks].b, al.b, accA0, 0, 0, 0);
      accA1 = __builtin_amdgcn_mfma_f32_16x16x32_bf16(ahi[1][ks].b, ah.b, accA1, 0, 0, 0);
      accA1 = __builtin_amdgcn_mfma_f32_16x16x32_bf16(alo[1][ks].b, ah.b, accA1, 0, 0, 0);
      accA1 = __builtin_amdgcn_mfma_f32_16x16x32_bf16(ahi[1][ks].b, al.b, accA1, 0, 0, 0);
      accB0 = __builtin_amdgcn_mfma_f32_16x16x32_bf16(ahi[0][ks].b, bh.b, accB0, 0, 0, 0);
      accB0 = __builtin_amdgcn_mfma_f32_16x16x32_bf16(alo[0][ks].b, bh.b, accB0, 0, 0, 0);
      accB0 = __builtin_amdgcn_mfma_f32_16x16x32_bf16(ahi[0][ks].b, bl.b, accB0, 0, 0, 0);
      accB1 = __builtin_amdgcn_mfma_f32_16x16x32_bf16(ahi[1][ks].b, bh.b, accB1, 0, 0, 0);
      accB1 = __builtin_amdgcn_mfma_f32_16x16x32_bf16(alo[1][ks].b, bh.b, accB1, 0, 0, 0);
      accB1 = __builtin_amdgcn_mfma_f32_16x16x32_bf16(ahi[1][ks].b, bl.b, accB1, 0, 0, 0);
    }
    float bv = biasA[nn];
#pragma unroll
    for (int r = 0; r < 4; r++) {
      int row0 = rowbase + q * 4 + r;
      int row1 = rowbase + 16 + q * 4 + r;
      if (row0 < nrows) {
        Aout[(size_t)row0 * HD + nn] = f2bf(accA0[r] + bv);
        Bout[(size_t)row0 * HD + nn] = f2bf(accB0[r]);
      }
      if (row1 < nrows) {
        Aout[(size_t)row1 * HD + nn] = f2bf(accA1[r] + bv);
        Bout[(size_t)row1 * HD + nn] = f2bf(accB1[r]);
      }
    }
  }
}

// ---------------- fused edge head (MFMA, CSR order: B-row L1-local) ----------------
// z1 = relu(A[s] + B[t] + ea@W1e) (bf16); z2 = relu(z1@W2 + b2); out[eid] = z2.w3 + b3
__global__ __launch_bounds__(256) void k_edge6(
    const unsigned short* __restrict__ Abf, const unsigned short* __restrict__ Bbf,
    const int* __restrict__ csrc, const int* __restrict__ ctgt, const int* __restrict__ ceid,
    const float* __restrict__ cea, const float* __restrict__ w1e,
    const unsigned short* __restrict__ w2t, const float* __restrict__ b2,
    const float* __restrict__ w3, const float* __restrict__ b3p,
    float* __restrict__ out, int E) {
  __shared__ float w1es[5 * 128];
  __shared__ __align__(16) unsigned w2s[64 * 64];  // 64 rows x 128 bf16, XOR-swizzled
  __shared__ float b2s[64], w3s[64];
  for (int i = threadIdx.x; i < 640; i += 256) w1es[i] = w1e[i];
  for (int e = threadIdx.x; e < 4096; e += 256) {
    int nrow = e >> 6, kk = e & 63;
    unsigned v = ((const unsigned*)w2t)[nrow * 64 + kk];
    int slot = (kk >> 2) ^ (nrow & 7);
    w2s[nrow * 64 + slot * 4 + (kk & 3)] = v;
  }
  if (threadIdx.x < 64) { b2s[threadIdx.x] = b2[threadIdx.x]; w3s[threadIdx.x] = w3[threadIdx.x]; }
  __syncthreads();
  const float b3v = b3p[0];
  int lane = threadIdx.x & 63;
  int q = lane >> 4, c = lane & 15;
  int wid = blockIdx.x * 4 + (threadIdx.x >> 6);
  int nw = gridDim.x * 4;
  int ntiles = (E + 15) >> 4;
  if (wid >= ntiles) return;
  // prologue: idx/ea for first tile, issue its gathers
  int sv, tv;
  float ev0, ev1, ev2, ev3, ev4;
  {
    int e = wid * 16 + c;
    int eld = (e < E) ? e : (E - 1);
    sv = csrc[eld]; tv = ctgt[eld];
    const float* pe = cea + (size_t)eld * 5;
    ev0 = pe[0]; ev1 = pe[1]; ev2 = pe[2]; ev3 = pe[3]; ev4 = pe[4];
  }
  uintx4 ga[4], gb[4];
  {
    const uintx4* pa = (const uintx4*)(Abf + (size_t)sv * 128);
    const uintx4* pb = (const uintx4*)(Bbf + (size_t)tv * 128);
#pragma unroll
    for (int ks = 0; ks < 4; ks++) { ga[ks] = pa[ks * 4 + q]; gb[ks] = pb[ks * 4 + q]; }
  }
  for (int tile = wid; tile < ntiles; tile += nw) {
    int tile2 = tile + nw;
    // prefetch next tile's indices + edge attrs (overlaps current gathers)
    int svn = 0, tvn = 0;
    float en0 = 0, en1 = 0, en2 = 0, en3 = 0, en4 = 0;
    if (tile2 < ntiles) {
      int e = tile2 * 16 + c;
      int eld = (e < E) ? e : (E - 1);
      svn = csrc[eld]; tvn = ctgt[eld];
      const float* pe = cea + (size_t)eld * 5;
      en0 = pe[0]; en1 = pe[1]; en2 = pe[2]; en3 = pe[3]; en4 = pe[4];
    }
    f32x4 acc[4] = {{0.f, 0.f, 0.f, 0.f}, {0.f, 0.f, 0.f, 0.f},
                    {0.f, 0.f, 0.f, 0.f}, {0.f, 0.f, 0.f, 0.f}};
#pragma unroll
    for (int ks = 0; ks < 4; ks++) {
      float z[8];
#pragma unroll
      for (int d = 0; d < 4; d++) {
        unsigned ua = ga[ks][d], ub = gb[ks][d];
        z[2 * d] = __builtin_bit_cast(float, ua << 16) + __builtin_bit_cast(float, ub << 16);
        z[2 * d + 1] = __builtin_bit_cast(float, ua & 0xffff0000u) +
                       __builtin_bit_cast(float, ub & 0xffff0000u);
      }
      int kbase = ks * 32 + q * 8;
      float evv[5] = {ev0, ev1, ev2, ev3, ev4};
#pragma unroll
      for (int i = 0; i < 5; i++) {
        const float4 wa = *(const float4*)&w1es[i * 128 + kbase];
        const float4 wb = *(const float4*)&w1es[i * 128 + kbase + 4];
        z[0] = fmaf(evv[i], wa.x, z[0]); z[1] = fmaf(evv[i], wa.y, z[1]);
        z[2] = fmaf(evv[i], wa.z, z[2]); z[3] = fmaf(evv[i], wa.w, z[3]);
        z[4] = fmaf(evv[i], wb.x, z[4]); z[5] = fmaf(evv[i], wb.y, z[5]);
        z[6] = fmaf(evv[i], wb.z, z[6]); z[7] = fmaf(evv[i], wb.w, z[7]);
      }
      Frag zh;
#pragma unroll
      for (int d = 0; d < 4; d++)
        zh.u4[d] = pkbf(fmaxf(z[2 * d], 0.f), fmaxf(z[2 * d + 1], 0.f));
#pragma unroll
      for (int nt = 0; nt < 4; nt++) {
        int nrow = nt * 16 + c;
        int slot = (ks * 4 + q) ^ (c & 7);
        Frag bf_;
        bf_.u4 = *(const uintx4*)&w2s[nrow * 64 + slot * 4];
        acc[nt] = __builtin_amdgcn_mfma_f32_16x16x32_bf16(zh.b, bf_.b, acc[nt], 0, 0, 0);
      }
    }
    // issue next tile's gathers now -- latency hides under epilogue + next idx load
    if (tile2 < ntiles) {
      const uintx4* pa = (const uintx4*)(Abf + (size_t)svn * 128);
      const uintx4* pb = (const uintx4*)(Bbf + (size_t)tvn * 128);
#pragma unroll
      for (int ks = 0; ks < 4; ks++) { ga[ks] = pa[ks * 4 + q]; gb[ks] = pb[ks * 4 + q]; }
      sv = svn; tv = tvn;
      ev0 = en0; ev1 = en1; ev2 = en2; ev3 = en3; ev4 = en4;
    }
    // epilogue: z2 relu + w3 dot + 16-lane reduce + scatter store by orig edge id
#pragma unroll
    for (int r = 0; r < 4; r++) {
      float v = 0.f;
#pragma unroll
      for (int nt = 0; nt < 4; nt++)
        v = fmaf(fmaxf(acc[nt][r] + b2s[nt * 16 + c], 0.f), w3s[nt * 16 + c], v);
      v += __shfl_xor(v, 1);
      v += __shfl_xor(v, 2);
      v += __shfl_xor(v, 4);
      v += __shfl_xor(v, 8);
      if (c == 0) {
        int eo = tile * 16 + q * 4 + r;
        if (eo < E) out[ceid[eo]] = v + b3v;
      }
    }
  }
}

extern "C" void kernel_launch(void* const* d_in, const int* in_sizes, int n_in,
                              void* d_out, int out_size, void* d_ws, size_t ws_size,
                              hipStream_t stream) {
  const float* x      = (const float*)d_in[0];
  const int*   ei     = (const int*)d_in[1];
  const float* ea     = (const float*)d_in[2];
  const float* w_enc  = (const float*)d_in[3];
  const float* b_enc  = (const float*)d_in[4];
  const float* g_enc  = (const float*)d_in[5];
  const float* be_enc = (const float*)d_in[6];
  const float* gcn_w  = (const float*)d_in[7];
  const float* gcn_b  = (const float*)d_in[8];
  const float* ln_g   = (const float*)d_in[9];
  const float* ln_b   = (const float*)d_in[10];
  const float* ec_w1  = (const float*)d_in[11];
  const float* ec_b1  = (const float*)d_in[12];
  const float* ec_w2  = (const float*)d_in[13];
  const float* ec_b2  = (const float*)d_in[14];
  const float* ec_w3  = (const float*)d_in[15];
  const float* ec_b3  = (const float*)d_in[16];
  float* out = (float*)d_out;

  int N = in_sizes[0] / 34;
  int E = in_sizes[1] / 2;
  const int* srcI = ei;
  const int* tgtI = ei + E;

  size_t NHb = (size_t)N * HD * 2;  // bf16 bytes per h-buffer
  char* p = (char*)d_ws;
  auto alloc = [&](size_t bytes) {
    char* r = p;
    p += (bytes + 255) & ~(size_t)255;
    return r;
  };
  unsigned short* h0hi  = (unsigned short*)alloc(NHb);
  unsigned short* h0lo  = (unsigned short*)alloc(NHb);
  unsigned short* h1hi  = (unsigned short*)alloc(NHb);
  unsigned short* h1lo  = (unsigned short*)alloc(NHb);
  unsigned short* agghi = (unsigned short*)alloc(NHb);
  unsigned short* agglo = (unsigned short*)alloc(NHb);
  unsigned short* Abf   = (unsigned short*)alloc(NHb);
  unsigned short* Bbf   = (unsigned short*)alloc(NHb);
  unsigned short* gwhi[3];
  unsigned short* gwlo[3];
  for (int l = 0; l < 3; l++) {
    gwhi[l] = (unsigned short*)alloc(128 * 128 * 2);
    gwlo[l] = (unsigned short*)alloc(128 * 128 * 2);
  }
  unsigned short* w1ahi = (unsigned short*)alloc(128 * 128 * 2);
  unsigned short* w1alo = (unsigned short*)alloc(128 * 128 * 2);
  unsigned short* w1bhi = (unsigned short*)alloc(128 * 128 * 2);
  unsigned short* w1blo = (unsigned short*)alloc(128 * 128 * 2);
  unsigned short* w2thi = (unsigned short*)alloc(64 * 128 * 2);
  unsigned short* w2tlo = (unsigned short*)alloc(64 * 128 * 2);
  int*   cnt     = (int*)alloc((size_t)N * 4);
  int*   rowptr  = (int*)alloc((size_t)(N + 1) * 4);
  int*   cursor  = (int*)alloc((size_t)N * 4);
  int*   csrc    = (int*)alloc((size_t)E * 4);
  int*   ctgt    = (int*)alloc((size_t)E * 4);
  int*   ceid    = (int*)alloc((size_t)E * 4);
  float* cea     = (float*)alloc((size_t)E * 5 * 4);
  float* csrnorm = (float*)alloc((size_t)E * 4);
  float* dinv    = (float*)alloc((size_t)N * 4);
  float* invdeg  = (float*)alloc((size_t)N * 4);
  int*   partial = (int*)alloc(4096 * 4);

  hipMemsetAsync(cnt, 0, (size_t)N * 4, stream);
  hipMemsetAsync(cursor, 0, (size_t)N * 4, stream);

  // weight prep
  for (int l = 0; l < 3; l++)
    k_prep<<<64, 256, 0, stream>>>(gcn_w + (size_t)l * 128 * 128, gwhi[l], gwlo[l], 128, 128);
  k_prep<<<64, 256, 0, stream>>>(ec_w1, w1ahi, w1alo, 128, 128);
  k_prep<<<64, 256, 0, stream>>>(ec_w1 + 133 * 128, w1bhi, w1blo, 128, 128);
  k_prep<<<32, 256, 0, stream>>>(ec_w2, w2thi, w2tlo, 128, 64);

  // CSR
  int gE = (E + 255) / 256, gN = (N + 255) / 256;
  int nb = (N + 1023) / 1024;
  k_count<<<gE, 256, 0, stream>>>(tgtI, cnt, E);
  k_scan1<<<nb, 1024, 0, stream>>>(cnt, rowptr, partial, N);
  k_scan2<<<1, 1024, 0, stream>>>(partial, nb);
  k_scan3<<<nb, 1024, 0, stream>>>(rowptr, partial, N, E);
  k_deg<<<gN, 256, 0, stream>>>(cnt, dinv, invdeg, N);
  k_fill3<<<gE, 256, 0, stream>>>(srcI, tgtI, rowptr, cursor, dinv, ea,
                                  csrc, ctgt, ceid, cea, csrnorm, E);

  // encoder
  k_encoder<<<(N + 3) / 4, 512, 0, stream>>>(x, w_enc, b_enc, g_enc, be_enc, h0hi, h0lo, N);

  // GCN stack: aggregate-then-GEMM (linearity), GEMM fused with LN/ReLU/residual
  unsigned short *chi = h0hi, *clo = h0lo, *nhi = h1hi, *nlo = h1lo;
  for (int l = 0; l < 3; l++) {
    k_agg4<<<(N + 3) / 4, 256, 0, stream>>>(chi, clo, rowptr, csrc, csrnorm, invdeg,
                                            agghi, agglo, N);
    k_gemm_ln<<<(N + 63) / 64, 256, 0, stream>>>(agghi, agglo, gwhi[l], gwlo[l],
                                                 gcn_b + l * HD, ln_g + l * HD, ln_b + l * HD,
                                                 chi, clo, nhi, nlo, N);
    unsigned short* t0 = chi; chi = nhi; nhi = t0;
    unsigned short* t1 = clo; clo = nlo; nlo = t1;
  }

  // edge-head node projections: A = h@W1a + b1 (bf16), B = h@W1b (bf16), fused
  int gG = (N + 127) / 128;
  k_gemm_mf2<<<gG, 256, 0, stream>>>(chi, clo, w1ahi, w1alo, w1bhi, w1blo, ec_b1, Abf, Bbf, N);

  // fused edge head (CSR order)
  k_edge6<<<2048, 256, 0, stream>>>(Abf, Bbf, csrc, ctgt, ceid, cea, ec_w1 + 128 * HD, w2thi,
                                    ec_b2, ec_w3, ec_b3, out, E);
}

// Round 7
// 996.183 us; speedup vs baseline: 1.4278x; 1.4278x over previous
//
#include <hip/hip_runtime.h>
#include <hip/hip_bf16.h>

#define HD 128

typedef __bf16 bf16x8 __attribute__((ext_vector_type(8)));
typedef float f32x4 __attribute__((ext_vector_type(4)));
typedef unsigned uintx4 __attribute__((ext_vector_type(4)));

union Frag { bf16x8 b; uintx4 u4; };

__device__ inline unsigned short f2bf(float f) {
  return __builtin_bit_cast(unsigned short, (__bf16)f);  // RNE via v_cvt
}
__device__ inline float bf2f(unsigned short h) {
  return __builtin_bit_cast(float, (unsigned)h << 16);
}
__device__ inline unsigned pkbf(float lo, float hi) {  // -> v_cvt_pk_bf16_f32
  return (unsigned)f2bf(lo) | ((unsigned)f2bf(hi) << 16);
}
__device__ inline float blo(unsigned u) { return __builtin_bit_cast(float, u << 16); }
__device__ inline float bhi(unsigned u) { return __builtin_bit_cast(float, u & 0xffff0000u); }

// ---------------- weight prep: fp32 [K][N] -> bf16 hi/lo transposed [N][K] ----------------
__global__ void k_prep(const float* __restrict__ w, unsigned short* __restrict__ hi,
                       unsigned short* __restrict__ lo, int K, int N) {
  int idx = blockIdx.x * 256 + threadIdx.x;
  if (idx >= K * N) return;
  int nn = idx / K, k = idx - nn * K;
  float v = w[k * N + nn];
  unsigned short h = f2bf(v);
  hi[idx] = h;
  lo[idx] = f2bf(v - bf2f(h));
}

// ---------------- CSR build ----------------
__global__ void k_count(const int* __restrict__ tgt, int* __restrict__ cnt, int E) {
  int e = blockIdx.x * 256 + threadIdx.x;
  if (e < E) atomicAdd(&cnt[tgt[e]], 1);
}

__global__ void k_scan1(const int* __restrict__ cnt, int* __restrict__ rowptr,
                        int* __restrict__ partial, int n) {
  __shared__ int lds[1024];
  int i = blockIdx.x * 1024 + threadIdx.x;
  int v = (i < n) ? cnt[i] : 0;
  lds[threadIdx.x] = v;
  __syncthreads();
  for (int off = 1; off < 1024; off <<= 1) {
    int t = (threadIdx.x >= (unsigned)off) ? lds[threadIdx.x - off] : 0;
    __syncthreads();
    lds[threadIdx.x] += t;
    __syncthreads();
  }
  if (i < n) rowptr[i] = lds[threadIdx.x] - v;  // exclusive
  if (threadIdx.x == 1023) partial[blockIdx.x] = lds[1023];
}

__global__ void k_scan2(int* __restrict__ partial, int nb) {
  __shared__ int lds[1024];
  int v = (threadIdx.x < (unsigned)nb) ? partial[threadIdx.x] : 0;
  lds[threadIdx.x] = v;
  __syncthreads();
  for (int off = 1; off < 1024; off <<= 1) {
    int t = (threadIdx.x >= (unsigned)off) ? lds[threadIdx.x - off] : 0;
    __syncthreads();
    lds[threadIdx.x] += t;
    __syncthreads();
  }
  if (threadIdx.x < (unsigned)nb) partial[threadIdx.x] = lds[threadIdx.x] - v;
}

__global__ void k_scan3(int* __restrict__ rowptr, const int* __restrict__ partial, int n, int E) {
  int i = blockIdx.x * 1024 + threadIdx.x;
  if (i < n) rowptr[i] += partial[blockIdx.x];
  if (blockIdx.x == 0 && threadIdx.x == 0) rowptr[n] = E;
}

__global__ void k_deg(const int* __restrict__ cnt, float* __restrict__ dinv,
                      float* __restrict__ invdeg, int n) {
  int i = blockIdx.x * 256 + threadIdx.x;
  if (i < n) {
    float d = (float)(cnt[i] + 1);  // +1 self loop
    dinv[i] = rsqrtf(d);
    invdeg[i] = 1.0f / d;
  }
}

// fill CSR with packed (src, norm) per slot: one 8B load at consume time
__global__ void k_fillp(const int* __restrict__ src, const int* __restrict__ tgt,
                        const int* __restrict__ rowptr, int* __restrict__ cursor,
                        const float* __restrict__ dinv, int2* __restrict__ csrn, int E) {
  int e = blockIdx.x * 256 + threadIdx.x;
  if (e < E) {
    int t = tgt[e], s = src[e];
    int pos = atomicAdd(&cursor[t], 1);
    float nv = dinv[s] * dinv[t];
    csrn[rowptr[t] + pos] = make_int2(s, __builtin_bit_cast(int, nv));
  }
}

// ---------------- node encoder: h = relu(LN(x@W + b)) -> bf16 hi/lo ----------------
__global__ void k_encoder(const float* __restrict__ x, const float* __restrict__ w,
                          const float* __restrict__ b, const float* __restrict__ lng,
                          const float* __restrict__ lnb, unsigned short* __restrict__ hhi,
                          unsigned short* __restrict__ hlo, int n) {
  __shared__ float xs[4 * 34];
  __shared__ float red[4][2][2];
  int g = threadIdx.x >> 7, j = threadIdx.x & 127;
  int node = blockIdx.x * 4 + g;
  int base = blockIdx.x * 4 * 34;
  if (threadIdx.x < 4 * 34) {
    int idx = base + threadIdx.x;
    xs[threadIdx.x] = (idx < n * 34) ? x[idx] : 0.f;
  }
  __syncthreads();
  float acc = b[j];
#pragma unroll
  for (int k = 0; k < 34; k++) acc = fmaf(xs[g * 34 + k], w[k * HD + j], acc);
  int lane = threadIdx.x & 63;
  int wg = (threadIdx.x >> 6) & 1;
  float s = acc, q = acc * acc;
#pragma unroll
  for (int off = 32; off; off >>= 1) { s += __shfl_xor(s, off); q += __shfl_xor(q, off); }
  if (lane == 0) { red[g][wg][0] = s; red[g][wg][1] = q; }
  __syncthreads();
  float st = red[g][0][0] + red[g][1][0], qt = red[g][0][1] + red[g][1][1];
  float mu = st * (1.f / HD);
  float var = qt * (1.f / HD) - mu * mu;
  float y = (acc - mu) * rsqrtf(var + 1e-5f) * lng[j] + lnb[j];
  if (node < n) {
    size_t idx = (size_t)node * HD + j;
    float r = fmaxf(y, 0.f);
    unsigned short hh = f2bf(r);
    hhi[idx] = hh;
    hlo[idx] = f2bf(r - bf2f(hh));
  }
}

// ---------------- FUSED GCN layer: gather-agg -> MFMA GEMM -> bias+LN+ReLU+residual ------
// Lane (q,c) aggregates cols [ks*32+q*8, +8) of node (rowbase+c) directly into the MFMA
// A-fragment position: no cross-lane reduce, no intermediate agg buffer.
__global__ __launch_bounds__(256) void k_fgl(
    const unsigned short* __restrict__ hhi, const unsigned short* __restrict__ hlo,
    const int* __restrict__ rowptr, const int2* __restrict__ csrn,
    const float* __restrict__ invdeg,
    const unsigned short* __restrict__ Whi, const unsigned short* __restrict__ Wlo,
    const float* __restrict__ bias, const float* __restrict__ lng, const float* __restrict__ lnb,
    unsigned short* __restrict__ houthi, unsigned short* __restrict__ houtlo, int nrows) {
  int lane = threadIdx.x & 63, wv = threadIdx.x >> 6;
  int q = lane >> 4, c = lane & 15;
  int rowbase = blockIdx.x * 64 + wv * 16;
  int node = rowbase + c;
  if (node >= nrows) node = nrows - 1;
  // self term: invdeg * (hi + lo)
  float acc[4][8];
  {
    float iv = invdeg[node];
    const uintx4* ph = (const uintx4*)(hhi + (size_t)node * 128);
    const uintx4* pl = (const uintx4*)(hlo + (size_t)node * 128);
#pragma unroll
    for (int ks = 0; ks < 4; ks++) {
      uintx4 sh = ph[ks * 4 + q], sl = pl[ks * 4 + q];
#pragma unroll
      for (int d = 0; d < 4; d++) {
        acc[ks][2 * d]     = iv * (blo(sh[d]) + blo(sl[d]));
        acc[ks][2 * d + 1] = iv * (bhi(sh[d]) + bhi(sl[d]));
      }
    }
  }
  // neighbor loop (per-lane divergent; 2-deep unroll for MLP)
  int e0 = rowptr[node], e1 = rowptr[node + 1];
  int e = e0;
  for (; e + 1 < e1; e += 2) {
    int2 v1 = csrn[e], v2 = csrn[e + 1];
    int s1 = v1.x, s2 = v2.x;
    float n1 = __builtin_bit_cast(float, v1.y), n2 = __builtin_bit_cast(float, v2.y);
    const uintx4* p1 = (const uintx4*)(hhi + (size_t)s1 * 128);
    const uintx4* p2 = (const uintx4*)(hhi + (size_t)s2 * 128);
    uintx4 g1[4], g2[4];
#pragma unroll
    for (int ks = 0; ks < 4; ks++) { g1[ks] = p1[ks * 4 + q]; g2[ks] = p2[ks * 4 + q]; }
#pragma unroll
    for (int ks = 0; ks < 4; ks++)
#pragma unroll
      for (int d = 0; d < 4; d++) {
        acc[ks][2 * d]     = fmaf(n1, blo(g1[ks][d]), acc[ks][2 * d]);
        acc[ks][2 * d + 1] = fmaf(n1, bhi(g1[ks][d]), acc[ks][2 * d + 1]);
        acc[ks][2 * d]     = fmaf(n2, blo(g2[ks][d]), acc[ks][2 * d]);
        acc[ks][2 * d + 1] = fmaf(n2, bhi(g2[ks][d]), acc[ks][2 * d + 1]);
      }
  }
  if (e < e1) {
    int2 v1 = csrn[e];
    int s1 = v1.x;
    float n1 = __builtin_bit_cast(float, v1.y);
    const uintx4* p1 = (const uintx4*)(hhi + (size_t)s1 * 128);
    uintx4 g1[4];
#pragma unroll
    for (int ks = 0; ks < 4; ks++) g1[ks] = p1[ks * 4 + q];
#pragma unroll
    for (int ks = 0; ks < 4; ks++)
#pragma unroll
      for (int d = 0; d < 4; d++) {
        acc[ks][2 * d]     = fmaf(n1, blo(g1[ks][d]), acc[ks][2 * d]);
        acc[ks][2 * d + 1] = fmaf(n1, bhi(g1[ks][d]), acc[ks][2 * d + 1]);
      }
  }
  // split fp32 agg -> bf16 hi/lo A-fragments (in place; acc dies here)
  Frag ahi[4], alo[4];
#pragma unroll
  for (int ks = 0; ks < 4; ks++)
#pragma unroll
    for (int d = 0; d < 4; d++) {
      float v0 = acc[ks][2 * d], v1 = acc[ks][2 * d + 1];
      unsigned short h0 = f2bf(v0), h1 = f2bf(v1);
      ahi[ks].u4[d] = (unsigned)h0 | ((unsigned)h1 << 16);
      alo[ks].u4[d] = pkbf(v0 - bf2f(h0), v1 - bf2f(h1));
    }
  // MFMA GEMM (bf16x3 split) over 8 n-tiles
  f32x4 gacc[8];
#pragma unroll
  for (int nt = 0; nt < 8; nt++) {
    f32x4 a = {0.f, 0.f, 0.f, 0.f};
    int nn = nt * 16 + c;
    const uintx4* pbh = (const uintx4*)(Whi + (size_t)nn * 128);
    const uintx4* pbl = (const uintx4*)(Wlo + (size_t)nn * 128);
#pragma unroll
    for (int ks = 0; ks < 4; ks++) {
      Frag bh, bl;
      bh.u4 = pbh[ks * 4 + q];
      bl.u4 = pbl[ks * 4 + q];
      a = __builtin_amdgcn_mfma_f32_16x16x32_bf16(ahi[ks].b, bh.b, a, 0, 0, 0);
      a = __builtin_amdgcn_mfma_f32_16x16x32_bf16(alo[ks].b, bh.b, a, 0, 0, 0);
      a = __builtin_amdgcn_mfma_f32_16x16x32_bf16(ahi[ks].b, bl.b, a, 0, 0, 0);
    }
    float bv = bias[nn];
#pragma unroll
    for (int r4 = 0; r4 < 4; r4++) gacc[nt][r4] = a[r4] + bv;
  }
  // per-row LayerNorm stats across the 16 c-lanes (C-layout: row = q*4+r4)
  float s[4] = {0, 0, 0, 0}, sq[4] = {0, 0, 0, 0};
#pragma unroll
  for (int nt = 0; nt < 8; nt++)
#pragma unroll
    for (int r4 = 0; r4 < 4; r4++) { float v = gacc[nt][r4]; s[r4] += v; sq[r4] += v * v; }
#pragma unroll
  for (int off = 1; off <= 8; off <<= 1)
#pragma unroll
    for (int r4 = 0; r4 < 4; r4++) {
      s[r4] += __shfl_xor(s[r4], off);
      sq[r4] += __shfl_xor(sq[r4], off);
    }
  float mu[4], rs[4];
#pragma unroll
  for (int r4 = 0; r4 < 4; r4++) {
    mu[r4] = s[r4] * (1.f / 128.f);
    float var = sq[r4] * (1.f / 128.f) - mu[r4] * mu[r4];
    rs[r4] = rsqrtf(var + 1e-5f);
  }
#pragma unroll
  for (int nt = 0; nt < 8; nt++) {
    int col = nt * 16 + c;
    float gv = lng[col], bb = lnb[col];
#pragma unroll
    for (int r4 = 0; r4 < 4; r4++) {
      int row = rowbase + q * 4 + r4;
      if (row < nrows) {
        size_t idx = (size_t)row * 128 + col;
        float y = (gacc[nt][r4] - mu[r4]) * rs[r4] * gv + bb;
        float rr = fmaxf(y, 0.f) + bf2f(hhi[idx]) + bf2f(hlo[idx]);
        unsigned short hh = f2bf(rr);
        houthi[idx] = hh;
        houtlo[idx] = f2bf(rr - bf2f(hh));
      }
    }
  }
}

// ---------------- fused A+B projection GEMM (bf16x3 split) -> bf16 out ----------
__global__ __launch_bounds__(256) void k_gemm_mf2(
    const unsigned short* __restrict__ Xhi, const unsigned short* __restrict__ Xlo,
    const unsigned short* __restrict__ Wahi, const unsigned short* __restrict__ Walo,
    const unsigned short* __restrict__ Wbhi, const unsigned short* __restrict__ Wblo,
    const float* __restrict__ biasA, unsigned short* __restrict__ Aout,
    unsigned short* __restrict__ Bout, int nrows) {
  int lane = threadIdx.x & 63, wv = threadIdx.x >> 6;
  int q = lane >> 4, c = lane & 15;
  int rowbase = blockIdx.x * 128 + wv * 32;
  Frag ahi[2][4], alo[2][4];
#pragma unroll
  for (int mt = 0; mt < 2; mt++) {
    int r = rowbase + 16 * mt + c;
    if (r >= nrows) r = nrows - 1;
    const uintx4* ph = (const uintx4*)(Xhi + (size_t)r * 128);
    const uintx4* pl = (const uintx4*)(Xlo + (size_t)r * 128);
#pragma unroll
    for (int ks = 0; ks < 4; ks++) {
      ahi[mt][ks].u4 = ph[ks * 4 + q];
      alo[mt][ks].u4 = pl[ks * 4 + q];
    }
  }
#pragma unroll
  for (int nt = 0; nt < 8; nt++) {
    f32x4 accA0 = {0.f, 0.f, 0.f, 0.f}, accA1 = {0.f, 0.f, 0.f, 0.f};
    f32x4 accB0 = {0.f, 0.f, 0.f, 0.f}, accB1 = {0.f, 0.f, 0.f, 0.f};
    int nn = nt * 16 + c;
    const uintx4* pah = (const uintx4*)(Wahi + (size_t)nn * 128);
    const uintx4* pal = (const uintx4*)(Walo + (size_t)nn * 128);
    const uintx4* pbh = (const uintx4*)(Wbhi + (size_t)nn * 128);
    const uintx4* pbl = (const uintx4*)(Wblo + (size_t)nn * 128);
#pragma unroll
    for (int ks = 0; ks < 4; ks++) {
      Frag ah, al, bh, bl;
      ah.u4 = pah[ks * 4 + q]; al.u4 = pal[ks * 4 + q];
      bh.u4 = pbh[ks * 4 + q]; bl.u4 = pbl[ks * 4 + q];
      accA0 = __builtin_amdgcn_mfma_f32_16x16x32_bf16(ahi[0][ks].b, ah.b, accA0, 0, 0, 0);
      accA0 = __builtin_amdgcn_mfma_f32_16x16x32_bf16(alo[0][ks].b, ah.b, accA0, 0, 0, 0);
      accA0 = __builtin_amdgcn_mfma_f32_16x16x32_bf16(ahi[0][ks].b, al.b, accA0, 0, 0, 0);
      accA1 = __builtin_amdgcn_mfma_f32_16x16x32_bf16(ahi[1][ks].b, ah.b, accA1, 0, 0, 0);
      accA1 = __builtin_amdgcn_mfma_f32_16x16x32_bf16(alo[1][ks].b, ah.b, accA1, 0, 0, 0);
      accA1 = __builtin_amdgcn_mfma_f32_16x16x32_bf16(ahi[1][ks].b, al.b, accA1, 0, 0, 0);
      accB0 = __builtin_amdgcn_mfma_f32_16x16x32_bf16(ahi[0][ks].b, bh.b, accB0, 0, 0, 0);
      accB0 = __builtin_amdgcn_mfma_f32_16x16x32_bf16(alo[0][ks].b, bh.b, accB0, 0, 0, 0);
      accB0 = __builtin_amdgcn_mfma_f32_16x16x32_bf16(ahi[0][ks].b, bl.b, accB0, 0, 0, 0);
      accB1 = __builtin_amdgcn_mfma_f32_16x16x32_bf16(ahi[1][ks].b, bh.b, accB1, 0, 0, 0);
      accB1 = __builtin_amdgcn_mfma_f32_16x16x32_bf16(alo[1][ks].b, bh.b, accB1, 0, 0, 0);
      accB1 = __builtin_amdgcn_mfma_f32_16x16x32_bf16(ahi[1][ks].b, bl.b, accB1, 0, 0, 0);
    }
    float bv = biasA[nn];
#pragma unroll
    for (int r = 0; r < 4; r++) {
      int row0 = rowbase + q * 4 + r;
      int row1 = rowbase + 16 + q * 4 + r;
      if (row0 < nrows) {
        Aout[(size_t)row0 * HD + nn] = f2bf(accA0[r] + bv);
        Bout[(size_t)row0 * HD + nn] = f2bf(accB0[r]);
      }
      if (row1 < nrows) {
        Aout[(size_t)row1 * HD + nn] = f2bf(accA1[r] + bv);
        Bout[(size_t)row1 * HD + nn] = f2bf(accB1[r]);
      }
    }
  }
}

// ---------------- fused edge head (MFMA, software-pipelined gathers) ----------------
// z1 = relu(A[s] + B[t] + ea@W1e) (bf16); z2 = relu(z1@W2 + b2); out = z2.w3 + b3
__global__ __launch_bounds__(256) void k_edge5(
    const unsigned short* __restrict__ Abf, const unsigned short* __restrict__ Bbf,
    const int* __restrict__ src, const int* __restrict__ tgt, const float* __restrict__ ea,
    const float* __restrict__ w1e, const unsigned short* __restrict__ w2t,
    const float* __restrict__ b2, const float* __restrict__ w3, const float* __restrict__ b3p,
    float* __restrict__ out, int E) {
  __shared__ float w1es[5 * 128];
  __shared__ __align__(16) unsigned w2s[64 * 64];  // 64 rows x 128 bf16, XOR-swizzled
  __shared__ float b2s[64], w3s[64];
  for (int i = threadIdx.x; i < 640; i += 256) w1es[i] = w1e[i];
  for (int e = threadIdx.x; e < 4096; e += 256) {
    int nrow = e >> 6, kk = e & 63;
    unsigned v = ((const unsigned*)w2t)[nrow * 64 + kk];
    int slot = (kk >> 2) ^ (nrow & 7);
    w2s[nrow * 64 + slot * 4 + (kk & 3)] = v;
  }
  if (threadIdx.x < 64) { b2s[threadIdx.x] = b2[threadIdx.x]; w3s[threadIdx.x] = w3[threadIdx.x]; }
  __syncthreads();
  const float b3v = b3p[0];
  int lane = threadIdx.x & 63;
  int q = lane >> 4, c = lane & 15;
  int wid = blockIdx.x * 4 + (threadIdx.x >> 6);
  int nw = gridDim.x * 4;
  int ntiles = (E + 15) >> 4;
  if (wid >= ntiles) return;
  // prologue: idx/ea for first tile, issue its gathers
  int sv, tv;
  float ev0, ev1, ev2, ev3, ev4;
  {
    int e = wid * 16 + c;
    int eld = (e < E) ? e : (E - 1);
    sv = src[eld]; tv = tgt[eld];
    const float* pe = ea + (size_t)eld * 5;
    ev0 = pe[0]; ev1 = pe[1]; ev2 = pe[2]; ev3 = pe[3]; ev4 = pe[4];
  }
  uintx4 ga[4], gb[4];
  {
    const uintx4* pa = (const uintx4*)(Abf + (size_t)sv * 128);
    const uintx4* pb = (const uintx4*)(Bbf + (size_t)tv * 128);
#pragma unroll
    for (int ks = 0; ks < 4; ks++) { ga[ks] = pa[ks * 4 + q]; gb[ks] = pb[ks * 4 + q]; }
  }
  for (int tile = wid; tile < ntiles; tile += nw) {
    int tile2 = tile + nw;
    // prefetch next tile's indices + edge attrs (overlaps current gathers)
    int svn = 0, tvn = 0;
    float en0 = 0, en1 = 0, en2 = 0, en3 = 0, en4 = 0;
    if (tile2 < ntiles) {
      int e = tile2 * 16 + c;
      int eld = (e < E) ? e : (E - 1);
      svn = src[eld]; tvn = tgt[eld];
      const float* pe = ea + (size_t)eld * 5;
      en0 = pe[0]; en1 = pe[1]; en2 = pe[2]; en3 = pe[3]; en4 = pe[4];
    }
    f32x4 acc[4] = {{0.f, 0.f, 0.f, 0.f}, {0.f, 0.f, 0.f, 0.f},
                    {0.f, 0.f, 0.f, 0.f}, {0.f, 0.f, 0.f, 0.f}};
#pragma unroll
    for (int ks = 0; ks < 4; ks++) {
      float z[8];
#pragma unroll
      for (int d = 0; d < 4; d++) {
        unsigned ua = ga[ks][d], ub = gb[ks][d];
        z[2 * d] = __builtin_bit_cast(float, ua << 16) + __builtin_bit_cast(float, ub << 16);
        z[2 * d + 1] = __builtin_bit_cast(float, ua & 0xffff0000u) +
                       __builtin_bit_cast(float, ub & 0xffff0000u);
      }
      int kbase = ks * 32 + q * 8;
      float evv[5] = {ev0, ev1, ev2, ev3, ev4};
#pragma unroll
      for (int i = 0; i < 5; i++) {
        const float4 wa = *(const float4*)&w1es[i * 128 + kbase];
        const float4 wb = *(const float4*)&w1es[i * 128 + kbase + 4];
        z[0] = fmaf(evv[i], wa.x, z[0]); z[1] = fmaf(evv[i], wa.y, z[1]);
        z[2] = fmaf(evv[i], wa.z, z[2]); z[3] = fmaf(evv[i], wa.w, z[3]);
        z[4] = fmaf(evv[i], wb.x, z[4]); z[5] = fmaf(evv[i], wb.y, z[5]);
        z[6] = fmaf(evv[i], wb.z, z[6]); z[7] = fmaf(evv[i], wb.w, z[7]);
      }
      Frag zh;
#pragma unroll
      for (int d = 0; d < 4; d++)
        zh.u4[d] = pkbf(fmaxf(z[2 * d], 0.f), fmaxf(z[2 * d + 1], 0.f));
#pragma unroll
      for (int nt = 0; nt < 4; nt++) {
        int nrow = nt * 16 + c;
        int slot = (ks * 4 + q) ^ (c & 7);
        Frag bf_;
        bf_.u4 = *(const uintx4*)&w2s[nrow * 64 + slot * 4];
        acc[nt] = __builtin_amdgcn_mfma_f32_16x16x32_bf16(zh.b, bf_.b, acc[nt], 0, 0, 0);
      }
    }
    // issue next tile's gathers now -- latency hides under epilogue + next idx load
    if (tile2 < ntiles) {
      const uintx4* pa = (const uintx4*)(Abf + (size_t)svn * 128);
      const uintx4* pb = (const uintx4*)(Bbf + (size_t)tvn * 128);
#pragma unroll
      for (int ks = 0; ks < 4; ks++) { ga[ks] = pa[ks * 4 + q]; gb[ks] = pb[ks * 4 + q]; }
      sv = svn; tv = tvn;
      ev0 = en0; ev1 = en1; ev2 = en2; ev3 = en3; ev4 = en4;
    }
    // epilogue: z2 relu + w3 dot + 16-lane reduce + store
#pragma unroll
    for (int r = 0; r < 4; r++) {
      float v = 0.f;
#pragma unroll
      for (int nt = 0; nt < 4; nt++)
        v = fmaf(fmaxf(acc[nt][r] + b2s[nt * 16 + c], 0.f), w3s[nt * 16 + c], v);
      v += __shfl_xor(v, 1);
      v += __shfl_xor(v, 2);
      v += __shfl_xor(v, 4);
      v += __shfl_xor(v, 8);
      if (c == 0) {
        int eo = tile * 16 + q * 4 + r;
        if (eo < E) out[eo] = v + b3v;
      }
    }
  }
}

extern "C" void kernel_launch(void* const* d_in, const int* in_sizes, int n_in,
                              void* d_out, int out_size, void* d_ws, size_t ws_size,
                              hipStream_t stream) {
  const float* x      = (const float*)d_in[0];
  const int*   ei     = (const int*)d_in[1];
  const float* ea     = (const float*)d_in[2];
  const float* w_enc  = (const float*)d_in[3];
  const float* b_enc  = (const float*)d_in[4];
  const float* g_enc  = (const float*)d_in[5];
  const float* be_enc = (const float*)d_in[6];
  const float* gcn_w  = (const float*)d_in[7];
  const float* gcn_b  = (const float*)d_in[8];
  const float* ln_g   = (const float*)d_in[9];
  const float* ln_b   = (const float*)d_in[10];
  const float* ec_w1  = (const float*)d_in[11];
  const float* ec_b1  = (const float*)d_in[12];
  const float* ec_w2  = (const float*)d_in[13];
  const float* ec_b2  = (const float*)d_in[14];
  const float* ec_w3  = (const float*)d_in[15];
  const float* ec_b3  = (const float*)d_in[16];
  float* out = (float*)d_out;

  int N = in_sizes[0] / 34;
  int E = in_sizes[1] / 2;
  const int* srcI = ei;
  const int* tgtI = ei + E;

  size_t NHb = (size_t)N * HD * 2;  // bf16 bytes per h-buffer
  char* p = (char*)d_ws;
  auto alloc = [&](size_t bytes) {
    char* r = p;
    p += (bytes + 255) & ~(size_t)255;
    return r;
  };
  unsigned short* h0hi  = (unsigned short*)alloc(NHb);
  unsigned short* h0lo  = (unsigned short*)alloc(NHb);
  unsigned short* h1hi  = (unsigned short*)alloc(NHb);
  unsigned short* h1lo  = (unsigned short*)alloc(NHb);
  unsigned short* Abf   = (unsigned short*)alloc(NHb);
  unsigned short* Bbf   = (unsigned short*)alloc(NHb);
  unsigned short* gwhi[3];
  unsigned short* gwlo[3];
  for (int l = 0; l < 3; l++) {
    gwhi[l] = (unsigned short*)alloc(128 * 128 * 2);
    gwlo[l] = (unsigned short*)alloc(128 * 128 * 2);
  }
  unsigned short* w1ahi = (unsigned short*)alloc(128 * 128 * 2);
  unsigned short* w1alo = (unsigned short*)alloc(128 * 128 * 2);
  unsigned short* w1bhi = (unsigned short*)alloc(128 * 128 * 2);
  unsigned short* w1blo = (unsigned short*)alloc(128 * 128 * 2);
  unsigned short* w2thi = (unsigned short*)alloc(64 * 128 * 2);
  unsigned short* w2tlo = (unsigned short*)alloc(64 * 128 * 2);
  int*   cnt     = (int*)alloc((size_t)N * 4);
  int*   rowptr  = (int*)alloc((size_t)(N + 1) * 4);
  int*   cursor  = (int*)alloc((size_t)N * 4);
  int2*  csrn    = (int2*)alloc((size_t)E * 8);
  float* dinv    = (float*)alloc((size_t)N * 4);
  float* invdeg  = (float*)alloc((size_t)N * 4);
  int*   partial = (int*)alloc(4096 * 4);

  hipMemsetAsync(cnt, 0, (size_t)N * 4, stream);
  hipMemsetAsync(cursor, 0, (size_t)N * 4, stream);

  // weight prep
  for (int l = 0; l < 3; l++)
    k_prep<<<64, 256, 0, stream>>>(gcn_w + (size_t)l * 128 * 128, gwhi[l], gwlo[l], 128, 128);
  k_prep<<<64, 256, 0, stream>>>(ec_w1, w1ahi, w1alo, 128, 128);
  k_prep<<<64, 256, 0, stream>>>(ec_w1 + 133 * 128, w1bhi, w1blo, 128, 128);
  k_prep<<<32, 256, 0, stream>>>(ec_w2, w2thi, w2tlo, 128, 64);

  // CSR
  int gE = (E + 255) / 256, gN = (N + 255) / 256;
  int nb = (N + 1023) / 1024;
  k_count<<<gE, 256, 0, stream>>>(tgtI, cnt, E);
  k_scan1<<<nb, 1024, 0, stream>>>(cnt, rowptr, partial, N);
  k_scan2<<<1, 1024, 0, stream>>>(partial, nb);
  k_scan3<<<nb, 1024, 0, stream>>>(rowptr, partial, N, E);
  k_deg<<<gN, 256, 0, stream>>>(cnt, dinv, invdeg, N);
  k_fillp<<<gE, 256, 0, stream>>>(srcI, tgtI, rowptr, cursor, dinv, csrn, E);

  // encoder
  k_encoder<<<(N + 3) / 4, 512, 0, stream>>>(x, w_enc, b_enc, g_enc, be_enc, h0hi, h0lo, N);

  // GCN stack: fully fused gather-agg + GEMM + LN + ReLU + residual per layer
  unsigned short *chi = h0hi, *clo = h0lo, *nhi = h1hi, *nlo = h1lo;
  for (int l = 0; l < 3; l++) {
    k_fgl<<<(N + 63) / 64, 256, 0, stream>>>(chi, clo, rowptr, csrn, invdeg,
                                             gwhi[l], gwlo[l], gcn_b + l * HD,
                                             ln_g + l * HD, ln_b + l * HD, nhi, nlo, N);
    unsigned short* t0 = chi; chi = nhi; nhi = t0;
    unsigned short* t1 = clo; clo = nlo; nlo = t1;
  }

  // edge-head node projections: A = h@W1a + b1 (bf16), B = h@W1b (bf16), fused
  int gG = (N + 127) / 128;
  k_gemm_mf2<<<gG, 256, 0, stream>>>(chi, clo, w1ahi, w1alo, w1bhi, w1blo, ec_b1, Abf, Bbf, N);

  // fused edge head (original edge order)
  k_edge5<<<2048, 256, 0, stream>>>(Abf, Bbf, srcI, tgtI, ea, ec_w1 + 128 * HD, w2thi,
                                    ec_b2, ec_w3, ec_b3, out, E);
}